// Round 5
// baseline (147.588 us; speedup 1.0000x reference)
//
#include <hip/hip_runtime.h>

// Problem constants (B=8, N_t=14, N_f=72, d_model=256, h=8, d_rpe=32)
#define B_    8
#define N_    1008
#define D_    256
#define H_    8
#define DK_   32
#define DA_   64
#define L2E_  1.4426950408889634f

typedef _Float16 half8_t __attribute__((ext_vector_type(8)));
typedef _Float16 half4_t __attribute__((ext_vector_type(4)));
typedef float    f32x4   __attribute__((ext_vector_type(4)));

#if defined(__has_builtin)
#if __has_builtin(__builtin_amdgcn_exp2f)
#define EXP2(x) __builtin_amdgcn_exp2f(x)
#else
#define EXP2(x) exp2f(x)
#endif
#else
#define EXP2(x) exp2f(x)
#endif

// ---------------------------------------------------------------------------
// K1: fused QKV projection (blocks 0..755) + RPE prep (blocks 756..791).
// (byte-identical to round 4 — unchanged for attribution)
// ---------------------------------------------------------------------------
__global__ __launch_bounds__(256, 4) void qkv_prep(
    const float* __restrict__ q_tok, const float* __restrict__ k_tok,
    const float* __restrict__ v_tok,
    const int* __restrict__ t_q, const int* __restrict__ f_q,
    const int* __restrict__ t_k, const int* __restrict__ f_k,
    const float* __restrict__ Wq, const float* __restrict__ Wk,
    const float* __restrict__ Wv, const float* __restrict__ W_rpe,
    _Float16* __restrict__ Qq, _Float16* __restrict__ Kq,
    _Float16* __restrict__ Uq, _Float16* __restrict__ Vr,
    _Float16* __restrict__ Vt)
{
    __shared__ __align__(16) _Float16 fw[8 * 4 * 64 * 8];   // 32 KB
    const int tid = threadIdx.x;
    const int lane = tid & 63, w = tid >> 6, quad = lane >> 4, l15 = lane & 15;
    const int id = blockIdx.x;

    if (id < 756) {
        const int mtile = id / 12, rem = id % 12, z = rem >> 2, ntile = rem & 3;
        const int m0 = mtile * 128, n0 = ntile * 64;
        const float* A = (z == 0) ? q_tok : (z == 1) ? k_tok : v_tok;
        const float* W = (z == 0) ? Wq : (z == 1) ? Wk : Wv;

        const float* Ar0 = &A[(size_t)(m0 + w * 16 + l15) * D_];
        const float* Ar1 = Ar0 + (size_t)64 * D_;
        float4 a00 = *(const float4*)&Ar0[quad * 8];
        float4 a01 = *(const float4*)&Ar0[quad * 8 + 4];
        float4 a10 = *(const float4*)&Ar1[quad * 8];
        float4 a11 = *(const float4*)&Ar1[quad * 8 + 4];

#pragma unroll
        for (int p = 0; p < 8; p++) {
            int g = p * 256 + tid;
            int ch = g >> 8, rem2 = g & 255, nt = rem2 >> 6, L = rem2 & 63;
            const float* src = &W[(size_t)(n0 + nt * 16 + (L & 15)) * D_ + ch * 32 + ((L >> 4) & 3) * 8];
            float4 w0 = *(const float4*)src;
            float4 w1 = *(const float4*)(src + 4);
            half8_t hv = {(_Float16)w0.x, (_Float16)w0.y, (_Float16)w0.z, (_Float16)w0.w,
                          (_Float16)w1.x, (_Float16)w1.y, (_Float16)w1.z, (_Float16)w1.w};
            *(half8_t*)&fw[g * 8] = hv;
        }
        __syncthreads();

        f32x4 acc[2][4] = {};
#pragma unroll
        for (int ch = 0; ch < 8; ch++) {
            half8_t af0 = {(_Float16)a00.x, (_Float16)a00.y, (_Float16)a00.z, (_Float16)a00.w,
                           (_Float16)a01.x, (_Float16)a01.y, (_Float16)a01.z, (_Float16)a01.w};
            half8_t af1 = {(_Float16)a10.x, (_Float16)a10.y, (_Float16)a10.z, (_Float16)a10.w,
                           (_Float16)a11.x, (_Float16)a11.y, (_Float16)a11.z, (_Float16)a11.w};
            if (ch < 7) {
                a00 = *(const float4*)&Ar0[(ch + 1) * 32 + quad * 8];
                a01 = *(const float4*)&Ar0[(ch + 1) * 32 + quad * 8 + 4];
                a10 = *(const float4*)&Ar1[(ch + 1) * 32 + quad * 8];
                a11 = *(const float4*)&Ar1[(ch + 1) * 32 + quad * 8 + 4];
            }
#pragma unroll
            for (int nt = 0; nt < 4; nt++) {
                half8_t bf = *(const half8_t*)&fw[((ch * 4 + nt) * 64 + lane) * 8];
                acc[0][nt] = __builtin_amdgcn_mfma_f32_16x16x32_f16(af0, bf, acc[0][nt], 0, 0, 0);
                acc[1][nt] = __builtin_amdgcn_mfma_f32_16x16x32_f16(af1, bf, acc[1][nt], 0, 0, 0);
            }
        }
        const float scale = (z == 0) ? 0.17677669529663687f * L2E_ : 1.0f;
#pragma unroll
        for (int mt = 0; mt < 2; mt++) {
            int mbase = m0 + mt * 64 + w * 16 + quad * 4;
            int b = mbase / N_;
            int q = mbase - b * N_;
            if (z < 2) {
                _Float16* o = (z == 0) ? Qq : Kq;
#pragma unroll
                for (int nt = 0; nt < 4; nt++) {
                    int n = n0 + nt * 16 + l15;
                    int hh = n >> 5, d = n & 31;
                    _Float16* dst = &o[(((size_t)(b * 8 + hh)) * N_ + q) * DK_ + d];
#pragma unroll
                    for (int r = 0; r < 4; r++)
                        dst[(size_t)r * DK_] = (_Float16)(acc[mt][nt][r] * scale);
                }
            } else {
#pragma unroll
                for (int nt = 0; nt < 4; nt++) {
                    int n = n0 + nt * 16 + l15;
                    int hh = n >> 5, d = n & 31;
                    half4_t o = {(_Float16)acc[mt][nt][0], (_Float16)acc[mt][nt][1],
                                 (_Float16)acc[mt][nt][2], (_Float16)acc[mt][nt][3]};
                    *(half4_t*)&Vt[(((size_t)(b * 8 + hh)) * DK_ + d) * N_ + q] = o;
                }
            }
        }
    } else {
        const float FR[8] = {1.f, 0.31622776601683794f, 0.1f, 0.03162277660168379f,
                             0.01f, 0.0031622776601683794f, 0.001f, 0.00031622776601683794f};
        int gid = (id - 756) * 256 + tid;
        if (gid < N_ * H_) {
            int q = gid >> 3, h = gid & 7;
            float tq = (float)t_q[q] * (1.f / 13.f);
            float fq = (float)f_q[q] * (1.f / 71.f);
            const float* Wh = W_rpe + h * 32;
            half8_t u0, u1, u2, u3;
#pragma unroll
            for (int i = 0; i < 8; i++) {
                float sa = __sinf(tq * FR[i]), ca = __cosf(tq * FR[i]);
                float sb = __sinf(fq * FR[i]), cb = __cosf(fq * FR[i]);
                u0[i] = (_Float16)(L2E_ * (Wh[i] * sa + Wh[8 + i] * ca));
                u1[i] = (_Float16)(L2E_ * (Wh[8 + i] * sa - Wh[i] * ca));
                u2[i] = (_Float16)(L2E_ * (Wh[16 + i] * sb + Wh[24 + i] * cb));
                u3[i] = (_Float16)(L2E_ * (Wh[24 + i] * sb - Wh[16 + i] * cb));
            }
            _Float16* dst = &Uq[((size_t)h * N_ + q) * DK_];
            *(half8_t*)(dst + 0) = u0;  *(half8_t*)(dst + 8) = u1;
            *(half8_t*)(dst + 16) = u2; *(half8_t*)(dst + 24) = u3;
        } else if (gid < N_ * H_ + N_) {
            int k = gid - N_ * H_;
            float tk = (float)t_k[k] * (1.f / 13.f);
            float fk = (float)f_k[k] * (1.f / 71.f);
            half8_t v0, v1, v2, v3;
#pragma unroll
            for (int i = 0; i < 8; i++) {
                v0[i] = (_Float16)__cosf(tk * FR[i]);
                v1[i] = (_Float16)__sinf(tk * FR[i]);
                v2[i] = (_Float16)__cosf(fk * FR[i]);
                v3[i] = (_Float16)__sinf(fk * FR[i]);
            }
            _Float16* dst = &Vr[(size_t)k * DK_];
            *(half8_t*)(dst + 0) = v0;  *(half8_t*)(dst + 8) = v1;
            *(half8_t*)(dst + 16) = v2; *(half8_t*)(dst + 24) = v3;
        }
    }
}

// ---------------------------------------------------------------------------
// K2: MFMA flash attention — 2 q-tiles per block (128 q-rows), grid (64,8).
// Halves device-wide K/V staging + barrier iterations; K-frags read once from
// LDS feed 2 MFMA; two independent softmax chains per wave give ILP.
// T13 defer-rescale: skip O/l rescale when __all(tmax - m <= 8) (P <= 2^8,
// fp16-safe). LDS 42 KB, grid 512 = 2 blocks/CU -> launch_bounds(256,2).
// ---------------------------------------------------------------------------
__global__ __launch_bounds__(256, 2) void attn(const _Float16* __restrict__ Qq,
    const _Float16* __restrict__ Kq, const _Float16* __restrict__ Uq,
    const _Float16* __restrict__ Vr, const _Float16* __restrict__ Vt,
    _Float16* __restrict__ AO)
{
    __shared__ __align__(16) _Float16 fkl[2][4096];     // 16 KB K|Vr frags (dbuf)
    __shared__ __align__(16) _Float16 fvl[2][2048];     // 8 KB  V^T frags (dbuf)
    __shared__ __align__(16) _Float16 pl[4][2][16][72]; // 18 KB per-wave/group P^T

    const int tid = threadIdx.x;
    const int lane = tid & 63, w = tid >> 6, quad = lane >> 4, l15 = lane & 15;
    const int bh = blockIdx.x, q0 = blockIdx.y * 128;   // bh fastest -> XCD locality
    const int b = bh >> 3, hh = bh & 7;
    const _Float16* Kb = Kq + (size_t)bh * N_ * DK_;
    const _Float16* Vb = Vt + (size_t)bh * DK_ * N_;

    const int s_l15 = tid & 15, s_quad = (tid >> 4) & 3;
    const int s_mt = tid >> 6;           // fk k-row group 0..3
    const int s_c = tid >> 7;            // fv k-col group 0..1
    const int s_mt2 = (tid >> 6) & 1;    // fv d-row group 0..1

    const int qgA = q0 + w * 16 + l15, qgB = qgA + 64;
    const int qcA = qgA < N_ ? qgA : N_ - 1;   // clamped lanes compute, don't store
    const int qcB = qgB < N_ ? qgB : N_ - 1;
    half8_t qf0A = *(const half8_t*)&Qq[((size_t)bh * N_ + qcA) * DK_ + quad * 8];
    half8_t qf1A = *(const half8_t*)&Uq[((size_t)hh * N_ + qcA) * DK_ + quad * 8];
    half8_t qf0B = *(const half8_t*)&Qq[((size_t)bh * N_ + qcB) * DK_ + quad * 8];
    half8_t qf1B = *(const half8_t*)&Uq[((size_t)hh * N_ + qcB) * DK_ + quad * 8];

    float mA = -1e30f, lA = 0.f, mB = -1e30f, lB = 0.f;
    f32x4 OA[2] = {}, OB[2] = {};

    {   // stage tile 0 directly
        int krow = s_mt * 16 + s_l15;
        *(half8_t*)&fkl[0][((s_mt * 2 + 0) * 64 + lane) * 8] =
            *(const half8_t*)&Kb[(size_t)krow * DK_ + s_quad * 8];
        *(half8_t*)&fkl[0][((s_mt * 2 + 1) * 64 + lane) * 8] =
            *(const half8_t*)&Vr[(size_t)krow * DK_ + s_quad * 8];
        int vrow = s_mt2 * 16 + s_l15;
        int vcol = s_c * 32 + s_quad * 8;
        *(half8_t*)&fvl[0][tid * 8] = *(const half8_t*)&Vb[(size_t)vrow * N_ + vcol];
    }
    __syncthreads();

    for (int kt = 0; kt < 16; kt++) {
        const int cb = kt & 1;
        // (A) T14: next-tile loads into registers only — ds_write deferred
        half8_t nk0, nk1, nv;
        if (kt < 15) {
            int k0n = (kt + 1) * 64;
            int krow = k0n + s_mt * 16 + s_l15;
            if (krow > N_ - 1) krow = N_ - 1;      // dup rows masked via S[3] at kt=15
            nk0 = *(const half8_t*)&Kb[(size_t)krow * DK_ + s_quad * 8];
            nk1 = *(const half8_t*)&Vr[(size_t)krow * DK_ + s_quad * 8];
            int vrow = s_mt2 * 16 + s_l15;
            int vcol = k0n + s_c * 32 + s_quad * 8;
            if (vcol > N_ - 8) vcol = N_ - 8;      // aligned dup, P=0 there
            nv = *(const half8_t*)&Vb[(size_t)vrow * N_ + vcol];
        }
        // (B) QK^T for both q-groups; K-frags read once, used twice
        f32x4 SA[4], SB[4];
        __builtin_amdgcn_s_setprio(1);
#pragma unroll
        for (int mt = 0; mt < 4; mt++) {
            half8_t kf0 = *(const half8_t*)&fkl[cb][((mt * 2 + 0) * 64 + lane) * 8];
            half8_t kf1 = *(const half8_t*)&fkl[cb][((mt * 2 + 1) * 64 + lane) * 8];
            f32x4 za = {0.f, 0.f, 0.f, 0.f};
            za = __builtin_amdgcn_mfma_f32_16x16x32_f16(kf0, qf0A, za, 0, 0, 0);
            SA[mt] = __builtin_amdgcn_mfma_f32_16x16x32_f16(kf1, qf1A, za, 0, 0, 0);
            f32x4 zb = {0.f, 0.f, 0.f, 0.f};
            zb = __builtin_amdgcn_mfma_f32_16x16x32_f16(kf0, qf0B, zb, 0, 0, 0);
            SB[mt] = __builtin_amdgcn_mfma_f32_16x16x32_f16(kf1, qf1B, zb, 0, 0, 0);
        }
        __builtin_amdgcn_s_setprio(0);
        if (kt == 15) {   // k 1008..1023 live entirely in mt=3
            SA[3] = (f32x4){-1e30f, -1e30f, -1e30f, -1e30f};
            SB[3] = (f32x4){-1e30f, -1e30f, -1e30f, -1e30f};
        }
        // softmax group A
        {
            float x0 = fmaxf(fmaxf(SA[0][0], SA[0][1]), fmaxf(SA[0][2], SA[0][3]));
            float x1 = fmaxf(fmaxf(SA[1][0], SA[1][1]), fmaxf(SA[1][2], SA[1][3]));
            float x2 = fmaxf(fmaxf(SA[2][0], SA[2][1]), fmaxf(SA[2][2], SA[2][3]));
            float x3 = fmaxf(fmaxf(SA[3][0], SA[3][1]), fmaxf(SA[3][2], SA[3][3]));
            float tmax = fmaxf(fmaxf(x0, x1), fmaxf(x2, x3));
            tmax = fmaxf(tmax, __shfl_xor(tmax, 16, 64));
            tmax = fmaxf(tmax, __shfl_xor(tmax, 32, 64));
            if (!__all(tmax - mA <= 8.f)) {     // T13: rescale only on real growth
                float mn = fmaxf(mA, tmax);
                float alpha = EXP2(mA - mn);
                mA = mn;  lA *= alpha;
                OA[0] = OA[0] * alpha;  OA[1] = OA[1] * alpha;
            }
            float tsum = 0.f;
#pragma unroll
            for (int mt = 0; mt < 4; mt++) {
                float p0 = EXP2(SA[mt][0] - mA), p1 = EXP2(SA[mt][1] - mA);
                float p2 = EXP2(SA[mt][2] - mA), p3 = EXP2(SA[mt][3] - mA);
                tsum += (p0 + p1) + (p2 + p3);
                half4_t ph = {(_Float16)p0, (_Float16)p1, (_Float16)p2, (_Float16)p3};
                *(half4_t*)&pl[w][0][l15][mt * 16 + quad * 4] = ph;
            }
            tsum += __shfl_xor(tsum, 16, 64);
            tsum += __shfl_xor(tsum, 32, 64);
            lA += tsum;
        }
        // softmax group B
        {
            float x0 = fmaxf(fmaxf(SB[0][0], SB[0][1]), fmaxf(SB[0][2], SB[0][3]));
            float x1 = fmaxf(fmaxf(SB[1][0], SB[1][1]), fmaxf(SB[1][2], SB[1][3]));
            float x2 = fmaxf(fmaxf(SB[2][0], SB[2][1]), fmaxf(SB[2][2], SB[2][3]));
            float x3 = fmaxf(fmaxf(SB[3][0], SB[3][1]), fmaxf(SB[3][2], SB[3][3]));
            float tmax = fmaxf(fmaxf(x0, x1), fmaxf(x2, x3));
            tmax = fmaxf(tmax, __shfl_xor(tmax, 16, 64));
            tmax = fmaxf(tmax, __shfl_xor(tmax, 32, 64));
            if (!__all(tmax - mB <= 8.f)) {
                float mn = fmaxf(mB, tmax);
                float alpha = EXP2(mB - mn);
                mB = mn;  lB *= alpha;
                OB[0] = OB[0] * alpha;  OB[1] = OB[1] * alpha;
            }
            float tsum = 0.f;
#pragma unroll
            for (int mt = 0; mt < 4; mt++) {
                float p0 = EXP2(SB[mt][0] - mB), p1 = EXP2(SB[mt][1] - mB);
                float p2 = EXP2(SB[mt][2] - mB), p3 = EXP2(SB[mt][3] - mB);
                tsum += (p0 + p1) + (p2 + p3);
                half4_t ph = {(_Float16)p0, (_Float16)p1, (_Float16)p2, (_Float16)p3};
                *(half4_t*)&pl[w][1][l15][mt * 16 + quad * 4] = ph;
            }
            tsum += __shfl_xor(tsum, 16, 64);
            tsum += __shfl_xor(tsum, 32, 64);
            lB += tsum;
        }
        // PV: O^T[d][q] += V^T . P^T; V-frags read once, used twice
        __builtin_amdgcn_s_setprio(1);
#pragma unroll
        for (int c = 0; c < 2; c++) {
            half8_t vfa = *(const half8_t*)&fvl[cb][((c * 2 + 0) * 64 + lane) * 8];
            half8_t vfb = *(const half8_t*)&fvl[cb][((c * 2 + 1) * 64 + lane) * 8];
            half8_t pfA = *(const half8_t*)&pl[w][0][l15][c * 32 + quad * 8];
            half8_t pfB = *(const half8_t*)&pl[w][1][l15][c * 32 + quad * 8];
            OA[0] = __builtin_amdgcn_mfma_f32_16x16x32_f16(vfa, pfA, OA[0], 0, 0, 0);
            OA[1] = __builtin_amdgcn_mfma_f32_16x16x32_f16(vfb, pfA, OA[1], 0, 0, 0);
            OB[0] = __builtin_amdgcn_mfma_f32_16x16x32_f16(vfa, pfB, OB[0], 0, 0, 0);
            OB[1] = __builtin_amdgcn_mfma_f32_16x16x32_f16(vfb, pfB, OB[1], 0, 0, 0);
        }
        __builtin_amdgcn_s_setprio(0);
        // (C) commit staged registers to the other LDS buffer
        if (kt < 15) {
            *(half8_t*)&fkl[cb ^ 1][((s_mt * 2 + 0) * 64 + lane) * 8] = nk0;
            *(half8_t*)&fkl[cb ^ 1][((s_mt * 2 + 1) * 64 + lane) * 8] = nk1;
            *(half8_t*)&fvl[cb ^ 1][tid * 8] = nv;
        }
        __syncthreads();
    }
    if (qgA < N_) {
        float inv = 1.f / lA;
#pragma unroll
        for (int mt2 = 0; mt2 < 2; mt2++) {
            half4_t o = {(_Float16)(OA[mt2][0] * inv), (_Float16)(OA[mt2][1] * inv),
                         (_Float16)(OA[mt2][2] * inv), (_Float16)(OA[mt2][3] * inv)};
            *(half4_t*)&AO[((size_t)b * N_ + qgA) * D_ + hh * DK_ + mt2 * 16 + quad * 4] = o;
        }
    }
    if (qgB < N_) {
        float inv = 1.f / lB;
#pragma unroll
        for (int mt2 = 0; mt2 < 2; mt2++) {
            half4_t o = {(_Float16)(OB[mt2][0] * inv), (_Float16)(OB[mt2][1] * inv),
                         (_Float16)(OB[mt2][2] * inv), (_Float16)(OB[mt2][3] * inv)};
            *(half4_t*)&AO[((size_t)b * N_ + qgB) * D_ + hh * DK_ + mt2 * 16 + quad * 4] = o;
        }
    }
}

// ---------------------------------------------------------------------------
// K3: output projection (byte-identical to round 4)
// ---------------------------------------------------------------------------
__global__ __launch_bounds__(256, 4) void out_gemm(const _Float16* __restrict__ A,
    const float* __restrict__ W, float* __restrict__ out)
{
    __shared__ __align__(16) _Float16 fw[8 * 4 * 64 * 8];   // 32 KB
    const int tid = threadIdx.x;
    const int lane = tid & 63, w = tid >> 6, quad = lane >> 4, l15 = lane & 15;
    const int id = blockIdx.x;
    const int m0 = (id >> 2) * 64, n0 = (id & 3) * 64;

    const _Float16* Ar = &A[(size_t)(m0 + w * 16 + l15) * D_];
    half8_t af = *(const half8_t*)&Ar[quad * 8];

#pragma unroll
    for (int p = 0; p < 8; p++) {
        int g = p * 256 + tid;
        int ch = g >> 8, rem2 = g & 255, nt = rem2 >> 6, L = rem2 & 63;
        const float* src = &W[(size_t)(n0 + nt * 16 + (L & 15)) * D_ + ch * 32 + ((L >> 4) & 3) * 8];
        float4 w0 = *(const float4*)src;
        float4 w1 = *(const float4*)(src + 4);
        half8_t hv = {(_Float16)w0.x, (_Float16)w0.y, (_Float16)w0.z, (_Float16)w0.w,
                      (_Float16)w1.x, (_Float16)w1.y, (_Float16)w1.z, (_Float16)w1.w};
        *(half8_t*)&fw[g * 8] = hv;
    }
    __syncthreads();

    f32x4 acc[4] = {};
#pragma unroll
    for (int ch = 0; ch < 8; ch++) {
        half8_t c0 = af;
        if (ch < 7) af = *(const half8_t*)&Ar[(ch + 1) * 32 + quad * 8];
#pragma unroll
        for (int nt = 0; nt < 4; nt++) {
            half8_t bf = *(const half8_t*)&fw[((ch * 4 + nt) * 64 + lane) * 8];
            acc[nt] = __builtin_amdgcn_mfma_f32_16x16x32_f16(c0, bf, acc[nt], 0, 0, 0);
        }
    }
    const int mbase = m0 + w * 16 + quad * 4;
#pragma unroll
    for (int nt = 0; nt < 4; nt++) {
        int n = n0 + nt * 16 + l15;
#pragma unroll
        for (int r = 0; r < 4; r++)
            out[(size_t)(mbase + r) * D_ + n] = acc[nt][r];
    }
}

// ---------------------------------------------------------------------------
extern "C" void kernel_launch(void* const* d_in, const int* in_sizes, int n_in,
                              void* d_out, int out_size, void* d_ws, size_t ws_size,
                              hipStream_t stream)
{
    const float* q_tokens = (const float*)d_in[0];
    const float* k_tokens = (const float*)d_in[1];
    const float* v_tokens = (const float*)d_in[2];
    const int*   t_q      = (const int*)d_in[3];
    const int*   f_q      = (const int*)d_in[4];
    const int*   t_k      = (const int*)d_in[5];
    const int*   f_k      = (const int*)d_in[6];
    // d_in[7]=N_t, d_in[8]=N_f hardcoded
    const float* W_q   = (const float*)d_in[9];
    const float* W_k   = (const float*)d_in[10];
    const float* W_v   = (const float*)d_in[11];
    const float* W_o   = (const float*)d_in[12];
    const float* W_rpe = (const float*)d_in[13];

    // ws layout (fp16), all 16B-aligned:
    _Float16* ws = (_Float16*)d_ws;
    _Float16* Qq = ws;                            // 64*1008*32 = 4.13 MB
    _Float16* Kq = Qq + (size_t)64 * N_ * DK_;    // 4.13 MB
    _Float16* Uq = Kq + (size_t)64 * N_ * DK_;    // 8*1008*32 = 516 KB
    _Float16* Vr = Uq + (size_t)H_ * N_ * DK_;    // 1008*32 = 64.5 KB
    _Float16* Vt = Vr + (size_t)N_ * DK_;         // 64*32*1008 = 4.13 MB
    _Float16* AO = Vt + (size_t)64 * DK_ * N_;    // 8064*256 = 4.13 MB

    qkv_prep<<<dim3(792), 256, 0, stream>>>(q_tokens, k_tokens, v_tokens,
                                            t_q, f_q, t_k, f_k,
                                            W_q, W_k, W_v, W_rpe,
                                            Qq, Kq, Uq, Vr, Vt);
    attn<<<dim3(64, 8), 256, 0, stream>>>(Qq, Kq, Uq, Vr, Vt, AO);
    out_gemm<<<dim3(504), 256, 0, stream>>>(AO, W_o, (float*)d_out);
}

// Round 6
// 145.078 us; speedup vs baseline: 1.0173x; 1.0173x over previous
//
#include <hip/hip_runtime.h>

// Problem constants (B=8, N_t=14, N_f=72, d_model=256, h=8, d_rpe=32)
#define B_    8
#define N_    1008
#define D_    256
#define H_    8
#define DK_   32
#define DA_   64
#define L2E_  1.4426950408889634f

typedef _Float16 half8_t __attribute__((ext_vector_type(8)));
typedef _Float16 half4_t __attribute__((ext_vector_type(4)));
typedef float    f32x4   __attribute__((ext_vector_type(4)));

#if defined(__has_builtin)
#if __has_builtin(__builtin_amdgcn_exp2f)
#define EXP2(x) __builtin_amdgcn_exp2f(x)
#else
#define EXP2(x) exp2f(x)
#endif
#else
#define EXP2(x) exp2f(x)
#endif

// ---------------------------------------------------------------------------
// K1: fused QKV projection (blocks 0..377, 128x128 tiles) + RPE prep (378..413).
// 128x128 tile halves A re-reads vs 128x64 (99 MB -> 48 MB): each A-tile now
// feeds 2 n-tiles instead of 4. Grid 414 blocks = ~1.6/CU (grid-limited), so
// the 64 KB LDS W-stage (2 blocks/CU cap) costs no occupancy headroom.
// W fp32->fp16 LDS-staged in B-frag order; A rows 1-deep reg prefetch.
// z=0: Qq*log2e/sqrt(32); z=1: Kq; z=2: Vt[bh][d][k].
// prep: U (h,q) -> Uq once; V-rpe (k) -> Vr once (dedup'd).
// ---------------------------------------------------------------------------
__global__ __launch_bounds__(256, 2) void qkv_prep(
    const float* __restrict__ q_tok, const float* __restrict__ k_tok,
    const float* __restrict__ v_tok,
    const int* __restrict__ t_q, const int* __restrict__ f_q,
    const int* __restrict__ t_k, const int* __restrict__ f_k,
    const float* __restrict__ Wq, const float* __restrict__ Wk,
    const float* __restrict__ Wv, const float* __restrict__ W_rpe,
    _Float16* __restrict__ Qq, _Float16* __restrict__ Kq,
    _Float16* __restrict__ Uq, _Float16* __restrict__ Vr,
    _Float16* __restrict__ Vt)
{
    __shared__ __align__(16) _Float16 fw[8 * 8 * 64 * 8];   // 64 KB
    const int tid = threadIdx.x;
    const int lane = tid & 63, w = tid >> 6, quad = lane >> 4, l15 = lane & 15;
    const int id = blockIdx.x;

    if (id < 378) {
        const int mtile = id / 6, rem = id % 6, z = rem >> 1, ntile = rem & 1;
        const int m0 = mtile * 128, n0 = ntile * 128;
        const float* A = (z == 0) ? q_tok : (z == 1) ? k_tok : v_tok;
        const float* W = (z == 0) ? Wq : (z == 1) ? Wk : Wv;

        // ch=0 A loads issued before staging: latency hides under stage+barrier
        const float* Ar0 = &A[(size_t)(m0 + w * 16 + l15) * D_];
        const float* Ar1 = Ar0 + (size_t)64 * D_;
        float4 a00 = *(const float4*)&Ar0[quad * 8];
        float4 a01 = *(const float4*)&Ar0[quad * 8 + 4];
        float4 a10 = *(const float4*)&Ar1[quad * 8];
        float4 a11 = *(const float4*)&Ar1[quad * 8 + 4];

#pragma unroll
        for (int p = 0; p < 16; p++) {
            int g = p * 256 + tid;
            int ch = g >> 9, rem2 = g & 511, nt = rem2 >> 6, L = rem2 & 63;
            const float* src = &W[(size_t)(n0 + nt * 16 + (L & 15)) * D_ + ch * 32 + ((L >> 4) & 3) * 8];
            float4 w0 = *(const float4*)src;
            float4 w1 = *(const float4*)(src + 4);
            half8_t hv = {(_Float16)w0.x, (_Float16)w0.y, (_Float16)w0.z, (_Float16)w0.w,
                          (_Float16)w1.x, (_Float16)w1.y, (_Float16)w1.z, (_Float16)w1.w};
            *(half8_t*)&fw[g * 8] = hv;
        }
        __syncthreads();

        f32x4 acc[2][8] = {};
#pragma unroll
        for (int ch = 0; ch < 8; ch++) {
            half8_t af0 = {(_Float16)a00.x, (_Float16)a00.y, (_Float16)a00.z, (_Float16)a00.w,
                           (_Float16)a01.x, (_Float16)a01.y, (_Float16)a01.z, (_Float16)a01.w};
            half8_t af1 = {(_Float16)a10.x, (_Float16)a10.y, (_Float16)a10.z, (_Float16)a10.w,
                           (_Float16)a11.x, (_Float16)a11.y, (_Float16)a11.z, (_Float16)a11.w};
            if (ch < 7) {   // 1-deep prefetch (compile-time guard, unrolled)
                a00 = *(const float4*)&Ar0[(ch + 1) * 32 + quad * 8];
                a01 = *(const float4*)&Ar0[(ch + 1) * 32 + quad * 8 + 4];
                a10 = *(const float4*)&Ar1[(ch + 1) * 32 + quad * 8];
                a11 = *(const float4*)&Ar1[(ch + 1) * 32 + quad * 8 + 4];
            }
#pragma unroll
            for (int nt = 0; nt < 8; nt++) {
                half8_t bf = *(const half8_t*)&fw[((ch * 8 + nt) * 64 + lane) * 8];
                acc[0][nt] = __builtin_amdgcn_mfma_f32_16x16x32_f16(af0, bf, acc[0][nt], 0, 0, 0);
                acc[1][nt] = __builtin_amdgcn_mfma_f32_16x16x32_f16(af1, bf, acc[1][nt], 0, 0, 0);
            }
        }
        const float scale = (z == 0) ? 0.17677669529663687f * L2E_ : 1.0f;
#pragma unroll
        for (int mt = 0; mt < 2; mt++) {
            int mbase = m0 + mt * 64 + w * 16 + quad * 4;
            int b = mbase / N_;
            int q = mbase - b * N_;          // 4-row group never crosses b (1008%4==0)
            if (z < 2) {
                _Float16* o = (z == 0) ? Qq : Kq;
#pragma unroll
                for (int nt = 0; nt < 8; nt++) {
                    int n = n0 + nt * 16 + l15;
                    int hh = n >> 5, d = n & 31;
                    _Float16* dst = &o[(((size_t)(b * 8 + hh)) * N_ + q) * DK_ + d];
#pragma unroll
                    for (int r = 0; r < 4; r++)
                        dst[(size_t)r * DK_] = (_Float16)(acc[mt][nt][r] * scale);
                }
            } else {
#pragma unroll
                for (int nt = 0; nt < 8; nt++) {
                    int n = n0 + nt * 16 + l15;
                    int hh = n >> 5, d = n & 31;
                    half4_t o = {(_Float16)acc[mt][nt][0], (_Float16)acc[mt][nt][1],
                                 (_Float16)acc[mt][nt][2], (_Float16)acc[mt][nt][3]};
                    *(half4_t*)&Vt[(((size_t)(b * 8 + hh)) * DK_ + d) * N_ + q] = o;
                }
            }
        }
    } else {
        const float FR[8] = {1.f, 0.31622776601683794f, 0.1f, 0.03162277660168379f,
                             0.01f, 0.0031622776601683794f, 0.001f, 0.00031622776601683794f};
        int gid = (id - 378) * 256 + tid;
        if (gid < N_ * H_) {
            int q = gid >> 3, h = gid & 7;
            float tq = (float)t_q[q] * (1.f / 13.f);
            float fq = (float)f_q[q] * (1.f / 71.f);
            const float* Wh = W_rpe + h * 32;
            half8_t u0, u1, u2, u3;
#pragma unroll
            for (int i = 0; i < 8; i++) {
                float sa = __sinf(tq * FR[i]), ca = __cosf(tq * FR[i]);
                float sb = __sinf(fq * FR[i]), cb = __cosf(fq * FR[i]);
                u0[i] = (_Float16)(L2E_ * (Wh[i] * sa + Wh[8 + i] * ca));
                u1[i] = (_Float16)(L2E_ * (Wh[8 + i] * sa - Wh[i] * ca));
                u2[i] = (_Float16)(L2E_ * (Wh[16 + i] * sb + Wh[24 + i] * cb));
                u3[i] = (_Float16)(L2E_ * (Wh[24 + i] * sb - Wh[16 + i] * cb));
            }
            _Float16* dst = &Uq[((size_t)h * N_ + q) * DK_];
            *(half8_t*)(dst + 0) = u0;  *(half8_t*)(dst + 8) = u1;
            *(half8_t*)(dst + 16) = u2; *(half8_t*)(dst + 24) = u3;
        } else if (gid < N_ * H_ + N_) {
            int k = gid - N_ * H_;
            float tk = (float)t_k[k] * (1.f / 13.f);
            float fk = (float)f_k[k] * (1.f / 71.f);
            half8_t v0, v1, v2, v3;
#pragma unroll
            for (int i = 0; i < 8; i++) {
                v0[i] = (_Float16)__cosf(tk * FR[i]);
                v1[i] = (_Float16)__sinf(tk * FR[i]);
                v2[i] = (_Float16)__cosf(fk * FR[i]);
                v3[i] = (_Float16)__sinf(fk * FR[i]);
            }
            _Float16* dst = &Vr[(size_t)k * DK_];
            *(half8_t*)(dst + 0) = v0;  *(half8_t*)(dst + 8) = v1;
            *(half8_t*)(dst + 16) = v2; *(half8_t*)(dst + 24) = v3;
        }
    }
}

// ---------------------------------------------------------------------------
// K2: MFMA flash attention (byte-identical to round 4 — measured best).
// S = Qq.Kq + Uq.Vr (rank-32 RPE via angle addition). Base-2 online softmax.
// grid (64 bh, 16 qt): XCD = bh%8 -> K/V L2-resident. T14 async-stage split.
// ---------------------------------------------------------------------------
__global__ __launch_bounds__(256, 4) void attn(const _Float16* __restrict__ Qq,
    const _Float16* __restrict__ Kq, const _Float16* __restrict__ Uq,
    const _Float16* __restrict__ Vr, const _Float16* __restrict__ Vt,
    _Float16* __restrict__ AO)
{
    __shared__ __align__(16) _Float16 fkl[2][4096];     // 16 KB K frags (dbuf)
    __shared__ __align__(16) _Float16 fvl[2][2048];     // 8 KB  V^T frags (dbuf)
    __shared__ __align__(16) _Float16 pl[4][16][72];    // 9 KB  per-wave P^T

    const int tid = threadIdx.x;
    const int lane = tid & 63, w = tid >> 6, quad = lane >> 4, l15 = lane & 15;
    const int bh = blockIdx.x, q0 = blockIdx.y * 64;
    const int b = bh >> 3, hh = bh & 7;
    const _Float16* Kb = Kq + (size_t)bh * N_ * DK_;
    const _Float16* Vb = Vt + (size_t)bh * DK_ * N_;

    const int s_l15 = tid & 15, s_quad = (tid >> 4) & 3;
    const int s_mt = tid >> 6;           // fk k-row group 0..3
    const int s_c = tid >> 7;            // fv k-col group 0..1
    const int s_mt2 = (tid >> 6) & 1;    // fv d-row group 0..1

    const int qg = q0 + w * 16 + l15;
    const int qc = qg < N_ ? qg : N_ - 1;     // clamped lanes compute, don't store
    half8_t qf0 = *(const half8_t*)&Qq[((size_t)bh * N_ + qc) * DK_ + quad * 8];
    half8_t qf1 = *(const half8_t*)&Uq[((size_t)hh * N_ + qc) * DK_ + quad * 8];

    float m_run = -1e30f, l_run = 0.f;
    f32x4 O[2] = {};

    {   // stage tile 0 directly
        int krow = s_mt * 16 + s_l15;
        *(half8_t*)&fkl[0][((s_mt * 2 + 0) * 64 + lane) * 8] =
            *(const half8_t*)&Kb[(size_t)krow * DK_ + s_quad * 8];
        *(half8_t*)&fkl[0][((s_mt * 2 + 1) * 64 + lane) * 8] =
            *(const half8_t*)&Vr[(size_t)krow * DK_ + s_quad * 8];
        int vrow = s_mt2 * 16 + s_l15;
        int vcol = s_c * 32 + s_quad * 8;
        *(half8_t*)&fvl[0][tid * 8] = *(const half8_t*)&Vb[(size_t)vrow * N_ + vcol];
    }
    __syncthreads();

    for (int kt = 0; kt < 16; kt++) {
        const int cb = kt & 1;
        // (A) T14: next-tile loads into registers only — ds_write deferred
        half8_t nk0, nk1, nv;
        if (kt < 15) {
            int k0n = (kt + 1) * 64;
            int krow = k0n + s_mt * 16 + s_l15;
            if (krow > N_ - 1) krow = N_ - 1;      // dup rows masked via S[3] at kt=15
            nk0 = *(const half8_t*)&Kb[(size_t)krow * DK_ + s_quad * 8];
            nk1 = *(const half8_t*)&Vr[(size_t)krow * DK_ + s_quad * 8];
            int vrow = s_mt2 * 16 + s_l15;
            int vcol = k0n + s_c * 32 + s_quad * 8;
            if (vcol > N_ - 8) vcol = N_ - 8;      // aligned dup, P=0 there
            nv = *(const half8_t*)&Vb[(size_t)vrow * N_ + vcol];
        }
        // (B) compute on current buffers
        f32x4 S[4];
        __builtin_amdgcn_s_setprio(1);
#pragma unroll
        for (int mt = 0; mt < 4; mt++) {
            half8_t kf0 = *(const half8_t*)&fkl[cb][((mt * 2 + 0) * 64 + lane) * 8];
            half8_t kf1 = *(const half8_t*)&fkl[cb][((mt * 2 + 1) * 64 + lane) * 8];
            f32x4 zz = {0.f, 0.f, 0.f, 0.f};
            zz = __builtin_amdgcn_mfma_f32_16x16x32_f16(kf0, qf0, zz, 0, 0, 0);
            S[mt] = __builtin_amdgcn_mfma_f32_16x16x32_f16(kf1, qf1, zz, 0, 0, 0);
        }
        __builtin_amdgcn_s_setprio(0);
        if (kt == 15)   // k 1008..1023 live entirely in mt=3
            S[3] = (f32x4){-1e30f, -1e30f, -1e30f, -1e30f};
        float x0 = fmaxf(fmaxf(S[0][0], S[0][1]), fmaxf(S[0][2], S[0][3]));
        float x1 = fmaxf(fmaxf(S[1][0], S[1][1]), fmaxf(S[1][2], S[1][3]));
        float x2 = fmaxf(fmaxf(S[2][0], S[2][1]), fmaxf(S[2][2], S[2][3]));
        float x3 = fmaxf(fmaxf(S[3][0], S[3][1]), fmaxf(S[3][2], S[3][3]));
        float tmax = fmaxf(fmaxf(x0, x1), fmaxf(x2, x3));
        tmax = fmaxf(tmax, __shfl_xor(tmax, 16, 64));
        tmax = fmaxf(tmax, __shfl_xor(tmax, 32, 64));
        float mnew = fmaxf(m_run, tmax);
        float alpha = EXP2(m_run - mnew);
        m_run = mnew;
        float tsum = 0.f;
#pragma unroll
        for (int mt = 0; mt < 4; mt++) {
            float p0 = EXP2(S[mt][0] - mnew), p1 = EXP2(S[mt][1] - mnew);
            float p2 = EXP2(S[mt][2] - mnew), p3 = EXP2(S[mt][3] - mnew);
            tsum += (p0 + p1) + (p2 + p3);
            half4_t ph = {(_Float16)p0, (_Float16)p1, (_Float16)p2, (_Float16)p3};
            *(half4_t*)&pl[w][l15][mt * 16 + quad * 4] = ph;  // P^T[q][k]
        }
        tsum += __shfl_xor(tsum, 16, 64);
        tsum += __shfl_xor(tsum, 32, 64);
        l_run = l_run * alpha + tsum;
        O[0] = O[0] * alpha;
        O[1] = O[1] * alpha;
        // PV: O^T[d][q] += V^T . P^T (same-wave LDS ordering, no barrier)
        __builtin_amdgcn_s_setprio(1);
#pragma unroll
        for (int c = 0; c < 2; c++) {
            half8_t pf = *(const half8_t*)&pl[w][l15][c * 32 + quad * 8];
            half8_t vfa = *(const half8_t*)&fvl[cb][((c * 2 + 0) * 64 + lane) * 8];
            half8_t vfb = *(const half8_t*)&fvl[cb][((c * 2 + 1) * 64 + lane) * 8];
            O[0] = __builtin_amdgcn_mfma_f32_16x16x32_f16(vfa, pf, O[0], 0, 0, 0);
            O[1] = __builtin_amdgcn_mfma_f32_16x16x32_f16(vfb, pf, O[1], 0, 0, 0);
        }
        __builtin_amdgcn_s_setprio(0);
        // (C) commit staged registers to the other LDS buffer
        if (kt < 15) {
            *(half8_t*)&fkl[cb ^ 1][((s_mt * 2 + 0) * 64 + lane) * 8] = nk0;
            *(half8_t*)&fkl[cb ^ 1][((s_mt * 2 + 1) * 64 + lane) * 8] = nk1;
            *(half8_t*)&fvl[cb ^ 1][tid * 8] = nv;
        }
        __syncthreads();
    }
    if (qg < N_) {
        float inv = 1.f / l_run;
#pragma unroll
        for (int mt2 = 0; mt2 < 2; mt2++) {
            half4_t o = {(_Float16)(O[mt2][0] * inv), (_Float16)(O[mt2][1] * inv),
                         (_Float16)(O[mt2][2] * inv), (_Float16)(O[mt2][3] * inv)};
            *(half4_t*)&AO[((size_t)b * N_ + qg) * D_ + hh * DK_ + mt2 * 16 + quad * 4] = o;
        }
    }
}

// ---------------------------------------------------------------------------
// K3: output projection (byte-identical to round 4)
// ---------------------------------------------------------------------------
__global__ __launch_bounds__(256, 4) void out_gemm(const _Float16* __restrict__ A,
    const float* __restrict__ W, float* __restrict__ out)
{
    __shared__ __align__(16) _Float16 fw[8 * 4 * 64 * 8];   // 32 KB
    const int tid = threadIdx.x;
    const int lane = tid & 63, w = tid >> 6, quad = lane >> 4, l15 = lane & 15;
    const int id = blockIdx.x;
    const int m0 = (id >> 2) * 64, n0 = (id & 3) * 64;

    const _Float16* Ar = &A[(size_t)(m0 + w * 16 + l15) * D_];
    half8_t af = *(const half8_t*)&Ar[quad * 8];

#pragma unroll
    for (int p = 0; p < 8; p++) {
        int g = p * 256 + tid;
        int ch = g >> 8, rem2 = g & 255, nt = rem2 >> 6, L = rem2 & 63;
        const float* src = &W[(size_t)(n0 + nt * 16 + (L & 15)) * D_ + ch * 32 + ((L >> 4) & 3) * 8];
        float4 w0 = *(const float4*)src;
        float4 w1 = *(const float4*)(src + 4);
        half8_t hv = {(_Float16)w0.x, (_Float16)w0.y, (_Float16)w0.z, (_Float16)w0.w,
                      (_Float16)w1.x, (_Float16)w1.y, (_Float16)w1.z, (_Float16)w1.w};
        *(half8_t*)&fw[g * 8] = hv;
    }
    __syncthreads();

    f32x4 acc[4] = {};
#pragma unroll
    for (int ch = 0; ch < 8; ch++) {
        half8_t c0 = af;
        if (ch < 7) af = *(const half8_t*)&Ar[(ch + 1) * 32 + quad * 8];
#pragma unroll
        for (int nt = 0; nt < 4; nt++) {
            half8_t bf = *(const half8_t*)&fw[((ch * 4 + nt) * 64 + lane) * 8];
            acc[nt] = __builtin_amdgcn_mfma_f32_16x16x32_f16(c0, bf, acc[nt], 0, 0, 0);
        }
    }
    const int mbase = m0 + w * 16 + quad * 4;
#pragma unroll
    for (int nt = 0; nt < 4; nt++) {
        int n = n0 + nt * 16 + l15;
#pragma unroll
        for (int r = 0; r < 4; r++)
            out[(size_t)(mbase + r) * D_ + n] = acc[nt][r];
    }
}

// ---------------------------------------------------------------------------
extern "C" void kernel_launch(void* const* d_in, const int* in_sizes, int n_in,
                              void* d_out, int out_size, void* d_ws, size_t ws_size,
                              hipStream_t stream)
{
    const float* q_tokens = (const float*)d_in[0];
    const float* k_tokens = (const float*)d_in[1];
    const float* v_tokens = (const float*)d_in[2];
    const int*   t_q      = (const int*)d_in[3];
    const int*   f_q      = (const int*)d_in[4];
    const int*   t_k      = (const int*)d_in[5];
    const int*   f_k      = (const int*)d_in[6];
    // d_in[7]=N_t, d_in[8]=N_f hardcoded
    const float* W_q   = (const float*)d_in[9];
    const float* W_k   = (const float*)d_in[10];
    const float* W_v   = (const float*)d_in[11];
    const float* W_o   = (const float*)d_in[12];
    const float* W_rpe = (const float*)d_in[13];

    // ws layout (fp16), all 16B-aligned:
    _Float16* ws = (_Float16*)d_ws;
    _Float16* Qq = ws;                            // 64*1008*32 = 4.13 MB
    _Float16* Kq = Qq + (size_t)64 * N_ * DK_;    // 4.13 MB
    _Float16* Uq = Kq + (size_t)64 * N_ * DK_;    // 8*1008*32 = 516 KB
    _Float16* Vr = Uq + (size_t)H_ * N_ * DK_;    // 1008*32 = 64.5 KB
    _Float16* Vt = Vr + (size_t)N_ * DK_;         // 64*32*1008 = 4.13 MB
    _Float16* AO = Vt + (size_t)64 * DK_ * N_;    // 8064*256 = 4.13 MB

    qkv_prep<<<dim3(414), 256, 0, stream>>>(q_tokens, k_tokens, v_tokens,
                                            t_q, f_q, t_k, f_k,
                                            W_q, W_k, W_v, W_rpe,
                                            Qq, Kq, Uq, Vr, Vt);
    attn<<<dim3(64, 16), 256, 0, stream>>>(Qq, Kq, Uq, Vr, Vt, AO);
    out_gemm<<<dim3(504), 256, 0, stream>>>(AO, W_o, (float*)d_out);
}

// Round 8
// 143.571 us; speedup vs baseline: 1.0280x; 1.0105x over previous
//
#include <hip/hip_runtime.h>

// Problem constants (B=8, N_t=14, N_f=72, d_model=256, h=8, d_rpe=32)
#define B_    8
#define N_    1008
#define D_    256
#define H_    8
#define DK_   32
#define DA_   64
#define L2E_  1.4426950408889634f

typedef _Float16 half8_t __attribute__((ext_vector_type(8)));
typedef _Float16 half4_t __attribute__((ext_vector_type(4)));
typedef float    f32x4   __attribute__((ext_vector_type(4)));

#if defined(__has_builtin)
#if __has_builtin(__builtin_amdgcn_exp2f)
#define EXP2(x) __builtin_amdgcn_exp2f(x)
#else
#define EXP2(x) exp2f(x)
#endif
#else
#define EXP2(x) exp2f(x)
#endif

// ---------------------------------------------------------------------------
// K1: fused QKV projection (blocks 0..377, 128x128 tiles) + RPE prep (378..413).
// Known-good round-6 kernel (measured 145.1 us total). Persistent/grid-barrier
// variants are abandoned: 3 protocols -> livelock (r2), stale-L2 stall (r3),
// hang (r7). Grid barriers at 1024-block scale are unshippable from HIP
// source on this chip (per-XCD L2 non-coherence).
// ---------------------------------------------------------------------------
__global__ __launch_bounds__(256, 2) void qkv_prep(
    const float* __restrict__ q_tok, const float* __restrict__ k_tok,
    const float* __restrict__ v_tok,
    const int* __restrict__ t_q, const int* __restrict__ f_q,
    const int* __restrict__ t_k, const int* __restrict__ f_k,
    const float* __restrict__ Wq, const float* __restrict__ Wk,
    const float* __restrict__ Wv, const float* __restrict__ W_rpe,
    _Float16* __restrict__ Qq, _Float16* __restrict__ Kq,
    _Float16* __restrict__ Uq, _Float16* __restrict__ Vr,
    _Float16* __restrict__ Vt)
{
    __shared__ __align__(16) _Float16 fw[8 * 8 * 64 * 8];   // 64 KB
    const int tid = threadIdx.x;
    const int lane = tid & 63, w = tid >> 6, quad = lane >> 4, l15 = lane & 15;
    const int id = blockIdx.x;

    if (id < 378) {
        const int mtile = id / 6, rem = id % 6, z = rem >> 1, ntile = rem & 1;
        const int m0 = mtile * 128, n0 = ntile * 128;
        const float* A = (z == 0) ? q_tok : (z == 1) ? k_tok : v_tok;
        const float* W = (z == 0) ? Wq : (z == 1) ? Wk : Wv;

        // ch=0 A loads issued before staging: latency hides under stage+barrier
        const float* Ar0 = &A[(size_t)(m0 + w * 16 + l15) * D_];
        const float* Ar1 = Ar0 + (size_t)64 * D_;
        float4 a00 = *(const float4*)&Ar0[quad * 8];
        float4 a01 = *(const float4*)&Ar0[quad * 8 + 4];
        float4 a10 = *(const float4*)&Ar1[quad * 8];
        float4 a11 = *(const float4*)&Ar1[quad * 8 + 4];

#pragma unroll
        for (int p = 0; p < 16; p++) {
            int g = p * 256 + tid;
            int ch = g >> 9, rem2 = g & 511, nt = rem2 >> 6, L = rem2 & 63;
            const float* src = &W[(size_t)(n0 + nt * 16 + (L & 15)) * D_ + ch * 32 + ((L >> 4) & 3) * 8];
            float4 w0 = *(const float4*)src;
            float4 w1 = *(const float4*)(src + 4);
            half8_t hv = {(_Float16)w0.x, (_Float16)w0.y, (_Float16)w0.z, (_Float16)w0.w,
                          (_Float16)w1.x, (_Float16)w1.y, (_Float16)w1.z, (_Float16)w1.w};
            *(half8_t*)&fw[g * 8] = hv;
        }
        __syncthreads();

        f32x4 acc[2][8] = {};
#pragma unroll
        for (int ch = 0; ch < 8; ch++) {
            half8_t af0 = {(_Float16)a00.x, (_Float16)a00.y, (_Float16)a00.z, (_Float16)a00.w,
                           (_Float16)a01.x, (_Float16)a01.y, (_Float16)a01.z, (_Float16)a01.w};
            half8_t af1 = {(_Float16)a10.x, (_Float16)a10.y, (_Float16)a10.z, (_Float16)a10.w,
                           (_Float16)a11.x, (_Float16)a11.y, (_Float16)a11.z, (_Float16)a11.w};
            if (ch < 7) {   // 1-deep prefetch (compile-time guard, unrolled)
                a00 = *(const float4*)&Ar0[(ch + 1) * 32 + quad * 8];
                a01 = *(const float4*)&Ar0[(ch + 1) * 32 + quad * 8 + 4];
                a10 = *(const float4*)&Ar1[(ch + 1) * 32 + quad * 8];
                a11 = *(const float4*)&Ar1[(ch + 1) * 32 + quad * 8 + 4];
            }
#pragma unroll
            for (int nt = 0; nt < 8; nt++) {
                half8_t bf = *(const half8_t*)&fw[((ch * 8 + nt) * 64 + lane) * 8];
                acc[0][nt] = __builtin_amdgcn_mfma_f32_16x16x32_f16(af0, bf, acc[0][nt], 0, 0, 0);
                acc[1][nt] = __builtin_amdgcn_mfma_f32_16x16x32_f16(af1, bf, acc[1][nt], 0, 0, 0);
            }
        }
        const float scale = (z == 0) ? 0.17677669529663687f * L2E_ : 1.0f;
#pragma unroll
        for (int mt = 0; mt < 2; mt++) {
            int mbase = m0 + mt * 64 + w * 16 + quad * 4;
            int b = mbase / N_;
            int q = mbase - b * N_;          // 4-row group never crosses b (1008%4==0)
            if (z < 2) {
                _Float16* o = (z == 0) ? Qq : Kq;
#pragma unroll
                for (int nt = 0; nt < 8; nt++) {
                    int n = n0 + nt * 16 + l15;
                    int hh = n >> 5, d = n & 31;
                    _Float16* dst = &o[(((size_t)(b * 8 + hh)) * N_ + q) * DK_ + d];
#pragma unroll
                    for (int r = 0; r < 4; r++)
                        dst[(size_t)r * DK_] = (_Float16)(acc[mt][nt][r] * scale);
                }
            } else {
#pragma unroll
                for (int nt = 0; nt < 8; nt++) {
                    int n = n0 + nt * 16 + l15;
                    int hh = n >> 5, d = n & 31;
                    half4_t o = {(_Float16)acc[mt][nt][0], (_Float16)acc[mt][nt][1],
                                 (_Float16)acc[mt][nt][2], (_Float16)acc[mt][nt][3]};
                    *(half4_t*)&Vt[(((size_t)(b * 8 + hh)) * DK_ + d) * N_ + q] = o;
                }
            }
        }
    } else {
        const float FR[8] = {1.f, 0.31622776601683794f, 0.1f, 0.03162277660168379f,
                             0.01f, 0.0031622776601683794f, 0.001f, 0.00031622776601683794f};
        int gid = (id - 378) * 256 + tid;
        if (gid < N_ * H_) {
            int q = gid >> 3, h = gid & 7;
            float tq = (float)t_q[q] * (1.f / 13.f);
            float fq = (float)f_q[q] * (1.f / 71.f);
            const float* Wh = W_rpe + h * 32;
            half8_t u0, u1, u2, u3;
#pragma unroll
            for (int i = 0; i < 8; i++) {
                float sa = __sinf(tq * FR[i]), ca = __cosf(tq * FR[i]);
                float sb = __sinf(fq * FR[i]), cb = __cosf(fq * FR[i]);
                u0[i] = (_Float16)(L2E_ * (Wh[i] * sa + Wh[8 + i] * ca));
                u1[i] = (_Float16)(L2E_ * (Wh[8 + i] * sa - Wh[i] * ca));
                u2[i] = (_Float16)(L2E_ * (Wh[16 + i] * sb + Wh[24 + i] * cb));
                u3[i] = (_Float16)(L2E_ * (Wh[24 + i] * sb - Wh[16 + i] * cb));
            }
            _Float16* dst = &Uq[((size_t)h * N_ + q) * DK_];
            *(half8_t*)(dst + 0) = u0;  *(half8_t*)(dst + 8) = u1;
            *(half8_t*)(dst + 16) = u2; *(half8_t*)(dst + 24) = u3;
        } else if (gid < N_ * H_ + N_) {
            int k = gid - N_ * H_;
            float tk = (float)t_k[k] * (1.f / 13.f);
            float fk = (float)f_k[k] * (1.f / 71.f);
            half8_t v0, v1, v2, v3;
#pragma unroll
            for (int i = 0; i < 8; i++) {
                v0[i] = (_Float16)__cosf(tk * FR[i]);
                v1[i] = (_Float16)__sinf(tk * FR[i]);
                v2[i] = (_Float16)__cosf(fk * FR[i]);
                v3[i] = (_Float16)__sinf(fk * FR[i]);
            }
            _Float16* dst = &Vr[(size_t)k * DK_];
            *(half8_t*)(dst + 0) = v0;  *(half8_t*)(dst + 8) = v1;
            *(half8_t*)(dst + 16) = v2; *(half8_t*)(dst + 24) = v3;
        }
    }
}

// ---------------------------------------------------------------------------
// K2: MFMA flash attention (round-4/6 measured-best).
// S = Qq.Kq + Uq.Vr (rank-32 RPE via angle addition). Base-2 online softmax.
// grid (64 bh, 16 qt): XCD = bh%8 -> K/V L2-resident. T14 async-stage split.
// ---------------------------------------------------------------------------
__global__ __launch_bounds__(256, 4) void attn(const _Float16* __restrict__ Qq,
    const _Float16* __restrict__ Kq, const _Float16* __restrict__ Uq,
    const _Float16* __restrict__ Vr, const _Float16* __restrict__ Vt,
    _Float16* __restrict__ AO)
{
    __shared__ __align__(16) _Float16 fkl[2][4096];     // 16 KB K frags (dbuf)
    __shared__ __align__(16) _Float16 fvl[2][2048];     // 8 KB  V^T frags (dbuf)
    __shared__ __align__(16) _Float16 pl[4][16][72];    // 9 KB  per-wave P^T

    const int tid = threadIdx.x;
    const int lane = tid & 63, w = tid >> 6, quad = lane >> 4, l15 = lane & 15;
    const int bh = blockIdx.x, q0 = blockIdx.y * 64;
    const int b = bh >> 3, hh = bh & 7;
    const _Float16* Kb = Kq + (size_t)bh * N_ * DK_;
    const _Float16* Vb = Vt + (size_t)bh * DK_ * N_;

    const int s_l15 = tid & 15, s_quad = (tid >> 4) & 3;
    const int s_mt = tid >> 6;           // fk k-row group 0..3
    const int s_c = tid >> 7;            // fv k-col group 0..1
    const int s_mt2 = (tid >> 6) & 1;    // fv d-row group 0..1

    const int qg = q0 + w * 16 + l15;
    const int qc = qg < N_ ? qg : N_ - 1;     // clamped lanes compute, don't store
    half8_t qf0 = *(const half8_t*)&Qq[((size_t)bh * N_ + qc) * DK_ + quad * 8];
    half8_t qf1 = *(const half8_t*)&Uq[((size_t)hh * N_ + qc) * DK_ + quad * 8];

    float m_run = -1e30f, l_run = 0.f;
    f32x4 O[2] = {};

    {   // stage tile 0 directly
        int krow = s_mt * 16 + s_l15;
        *(half8_t*)&fkl[0][((s_mt * 2 + 0) * 64 + lane) * 8] =
            *(const half8_t*)&Kb[(size_t)krow * DK_ + s_quad * 8];
        *(half8_t*)&fkl[0][((s_mt * 2 + 1) * 64 + lane) * 8] =
            *(const half8_t*)&Vr[(size_t)krow * DK_ + s_quad * 8];
        int vrow = s_mt2 * 16 + s_l15;
        int vcol = s_c * 32 + s_quad * 8;
        *(half8_t*)&fvl[0][tid * 8] = *(const half8_t*)&Vb[(size_t)vrow * N_ + vcol];
    }
    __syncthreads();

    for (int kt = 0; kt < 16; kt++) {
        const int cb = kt & 1;
        // (A) T14: next-tile loads into registers only — ds_write deferred
        half8_t nk0, nk1, nv;
        if (kt < 15) {
            int k0n = (kt + 1) * 64;
            int krow = k0n + s_mt * 16 + s_l15;
            if (krow > N_ - 1) krow = N_ - 1;      // dup rows masked via S[3] at kt=15
            nk0 = *(const half8_t*)&Kb[(size_t)krow * DK_ + s_quad * 8];
            nk1 = *(const half8_t*)&Vr[(size_t)krow * DK_ + s_quad * 8];
            int vrow = s_mt2 * 16 + s_l15;
            int vcol = k0n + s_c * 32 + s_quad * 8;
            if (vcol > N_ - 8) vcol = N_ - 8;      // aligned dup, P=0 there
            nv = *(const half8_t*)&Vb[(size_t)vrow * N_ + vcol];
        }
        // (B) compute on current buffers
        f32x4 S[4];
        __builtin_amdgcn_s_setprio(1);
#pragma unroll
        for (int mt = 0; mt < 4; mt++) {
            half8_t kf0 = *(const half8_t*)&fkl[cb][((mt * 2 + 0) * 64 + lane) * 8];
            half8_t kf1 = *(const half8_t*)&fkl[cb][((mt * 2 + 1) * 64 + lane) * 8];
            f32x4 zz = {0.f, 0.f, 0.f, 0.f};
            zz = __builtin_amdgcn_mfma_f32_16x16x32_f16(kf0, qf0, zz, 0, 0, 0);
            S[mt] = __builtin_amdgcn_mfma_f32_16x16x32_f16(kf1, qf1, zz, 0, 0, 0);
        }
        __builtin_amdgcn_s_setprio(0);
        if (kt == 15)   // k 1008..1023 live entirely in mt=3
            S[3] = (f32x4){-1e30f, -1e30f, -1e30f, -1e30f};
        float x0 = fmaxf(fmaxf(S[0][0], S[0][1]), fmaxf(S[0][2], S[0][3]));
        float x1 = fmaxf(fmaxf(S[1][0], S[1][1]), fmaxf(S[1][2], S[1][3]));
        float x2 = fmaxf(fmaxf(S[2][0], S[2][1]), fmaxf(S[2][2], S[2][3]));
        float x3 = fmaxf(fmaxf(S[3][0], S[3][1]), fmaxf(S[3][2], S[3][3]));
        float tmax = fmaxf(fmaxf(x0, x1), fmaxf(x2, x3));
        tmax = fmaxf(tmax, __shfl_xor(tmax, 16, 64));
        tmax = fmaxf(tmax, __shfl_xor(tmax, 32, 64));
        float mnew = fmaxf(m_run, tmax);
        float alpha = EXP2(m_run - mnew);
        m_run = mnew;
        float tsum = 0.f;
#pragma unroll
        for (int mt = 0; mt < 4; mt++) {
            float p0 = EXP2(S[mt][0] - mnew), p1 = EXP2(S[mt][1] - mnew);
            float p2 = EXP2(S[mt][2] - mnew), p3 = EXP2(S[mt][3] - mnew);
            tsum += (p0 + p1) + (p2 + p3);
            half4_t ph = {(_Float16)p0, (_Float16)p1, (_Float16)p2, (_Float16)p3};
            *(half4_t*)&pl[w][l15][mt * 16 + quad * 4] = ph;  // P^T[q][k]
        }
        tsum += __shfl_xor(tsum, 16, 64);
        tsum += __shfl_xor(tsum, 32, 64);
        l_run = l_run * alpha + tsum;
        O[0] = O[0] * alpha;
        O[1] = O[1] * alpha;
        // PV: O^T[d][q] += V^T . P^T (same-wave LDS ordering, no barrier)
        __builtin_amdgcn_s_setprio(1);
#pragma unroll
        for (int c = 0; c < 2; c++) {
            half8_t pf = *(const half8_t*)&pl[w][l15][c * 32 + quad * 8];
            half8_t vfa = *(const half8_t*)&fvl[cb][((c * 2 + 0) * 64 + lane) * 8];
            half8_t vfb = *(const half8_t*)&fvl[cb][((c * 2 + 1) * 64 + lane) * 8];
            O[0] = __builtin_amdgcn_mfma_f32_16x16x32_f16(vfa, pf, O[0], 0, 0, 0);
            O[1] = __builtin_amdgcn_mfma_f32_16x16x32_f16(vfb, pf, O[1], 0, 0, 0);
        }
        __builtin_amdgcn_s_setprio(0);
        // (C) commit staged registers to the other LDS buffer
        if (kt < 15) {
            *(half8_t*)&fkl[cb ^ 1][((s_mt * 2 + 0) * 64 + lane) * 8] = nk0;
            *(half8_t*)&fkl[cb ^ 1][((s_mt * 2 + 1) * 64 + lane) * 8] = nk1;
            *(half8_t*)&fvl[cb ^ 1][tid * 8] = nv;
        }
        __syncthreads();
    }
    if (qg < N_) {
        float inv = 1.f / l_run;
#pragma unroll
        for (int mt2 = 0; mt2 < 2; mt2++) {
            half4_t o = {(_Float16)(O[mt2][0] * inv), (_Float16)(O[mt2][1] * inv),
                         (_Float16)(O[mt2][2] * inv), (_Float16)(O[mt2][3] * inv)};
            *(half4_t*)&AO[((size_t)b * N_ + qg) * D_ + hh * DK_ + mt2 * 16 + quad * 4] = o;
        }
    }
}

// ---------------------------------------------------------------------------
// K3: output projection (round-4/6 measured-best). 64x64 tiles, 504 blocks.
// ---------------------------------------------------------------------------
__global__ __launch_bounds__(256, 4) void out_gemm(const _Float16* __restrict__ A,
    const float* __restrict__ W, float* __restrict__ out)
{
    __shared__ __align__(16) _Float16 fw[8 * 4 * 64 * 8];   // 32 KB
    const int tid = threadIdx.x;
    const int lane = tid & 63, w = tid >> 6, quad = lane >> 4, l15 = lane & 15;
    const int id = blockIdx.x;
    const int m0 = (id >> 2) * 64, n0 = (id & 3) * 64;

    const _Float16* Ar = &A[(size_t)(m0 + w * 16 + l15) * D_];
    half8_t af = *(const half8_t*)&Ar[quad * 8];

#pragma unroll
    for (int p = 0; p < 8; p++) {
        int g = p * 256 + tid;
        int ch = g >> 8, rem2 = g & 255, nt = rem2 >> 6, L = rem2 & 63;
        const float* src = &W[(size_t)(n0 + nt * 16 + (L & 15)) * D_ + ch * 32 + ((L >> 4) & 3) * 8];
        float4 w0 = *(const float4*)src;
        float4 w1 = *(const float4*)(src + 4);
        half8_t hv = {(_Float16)w0.x, (_Float16)w0.y, (_Float16)w0.z, (_Float16)w0.w,
                      (_Float16)w1.x, (_Float16)w1.y, (_Float16)w1.z, (_Float16)w1.w};
        *(half8_t*)&fw[g * 8] = hv;
    }
    __syncthreads();

    f32x4 acc[4] = {};
#pragma unroll
    for (int ch = 0; ch < 8; ch++) {
        half8_t c0 = af;
        if (ch < 7) af = *(const half8_t*)&Ar[(ch + 1) * 32 + quad * 8];
#pragma unroll
        for (int nt = 0; nt < 4; nt++) {
            half8_t bf = *(const half8_t*)&fw[((ch * 4 + nt) * 64 + lane) * 8];
            acc[nt] = __builtin_amdgcn_mfma_f32_16x16x32_f16(c0, bf, acc[nt], 0, 0, 0);
        }
    }
    const int mbase = m0 + w * 16 + quad * 4;
#pragma unroll
    for (int nt = 0; nt < 4; nt++) {
        int n = n0 + nt * 16 + l15;
#pragma unroll
        for (int r = 0; r < 4; r++)
            out[(size_t)(mbase + r) * D_ + n] = acc[nt][r];
    }
}

// ---------------------------------------------------------------------------
extern "C" void kernel_launch(void* const* d_in, const int* in_sizes, int n_in,
                              void* d_out, int out_size, void* d_ws, size_t ws_size,
                              hipStream_t stream)
{
    const float* q_tokens = (const float*)d_in[0];
    const float* k_tokens = (const float*)d_in[1];
    const float* v_tokens = (const float*)d_in[2];
    const int*   t_q      = (const int*)d_in[3];
    const int*   f_q      = (const int*)d_in[4];
    const int*   t_k      = (const int*)d_in[5];
    const int*   f_k      = (const int*)d_in[6];
    // d_in[7]=N_t, d_in[8]=N_f hardcoded
    const float* W_q   = (const float*)d_in[9];
    const float* W_k   = (const float*)d_in[10];
    const float* W_v   = (const float*)d_in[11];
    const float* W_o   = (const float*)d_in[12];
    const float* W_rpe = (const float*)d_in[13];

    // ws layout (fp16), all 16B-aligned:
    _Float16* ws = (_Float16*)d_ws;
    _Float16* Qq = ws;                            // 64*1008*32 = 4.13 MB
    _Float16* Kq = Qq + (size_t)64 * N_ * DK_;    // 4.13 MB
    _Float16* Uq = Kq + (size_t)64 * N_ * DK_;    // 8*1008*32 = 516 KB
    _Float16* Vr = Uq + (size_t)H_ * N_ * DK_;    // 1008*32 = 64.5 KB
    _Float16* Vt = Vr + (size_t)N_ * DK_;         // 64*32*1008 = 4.13 MB
    _Float16* AO = Vt + (size_t)64 * DK_ * N_;    // 8064*256 = 4.13 MB

    qkv_prep<<<dim3(414), 256, 0, stream>>>(q_tokens, k_tokens, v_tokens,
                                            t_q, f_q, t_k, f_k,
                                            W_q, W_k, W_v, W_rpe,
                                            Qq, Kq, Uq, Vr, Vt);
    attn<<<dim3(64, 16), 256, 0, stream>>>(Qq, Kq, Uq, Vr, Vt, AO);
    out_gemm<<<dim3(504), 256, 0, stream>>>(AO, W_o, (float*)d_out);
}